// Round 15
// baseline (80.418 us; speedup 1.0000x reference)
//
#include <hip/hip_runtime.h>
#include <cstdint>
#include <cstddef>

// Problem constants
#define B_    16
#define S_    1024
#define D_    512
#define P_    256
#define MAXS_ 2048

typedef unsigned short u16;
typedef unsigned int   u32;
typedef _Float16 f16;
typedef _Float16 f16x8 __attribute__((ext_vector_type(8)));
typedef float  f32x4  __attribute__((ext_vector_type(4)));
typedef unsigned short u16x4 __attribute__((ext_vector_type(4)));
typedef unsigned short u16x8 __attribute__((ext_vector_type(8)));

__device__ __forceinline__ void gld_lds16(const void* g, void* l) {
  __builtin_amdgcn_global_load_lds(
      (const __attribute__((address_space(1))) u32*)g,
      (__attribute__((address_space(3))) u32*)l, 16, 0, 0);
}

__device__ __forceinline__ u16 f2h(float f) {
  return __builtin_bit_cast(u16, (f16)f);
}
__device__ __forceinline__ float h2f(u16 h) {
  return (float)__builtin_bit_cast(f16, h);
}

// Batch-affinity XCD swizzle (round 11, kept): XCD t owns batches 2t, 2t+1.
template<int BPB>
__device__ __forceinline__ void xcd_map(int L, int& bz, int& r) {
  const int t = L & 7;
  const int j = L >> 3;
  bz = (t << 1) | (j / BPB);
  r  = j % BPB;
}

// ---------------------------------------------------------------------------
// f32 -> f16 convert (data, W)  [frozen]
// ---------------------------------------------------------------------------
__global__ void convert_f16_kernel(const float* __restrict__ src, u16* __restrict__ dst, long n4) {
  long stride = (long)gridDim.x * blockDim.x;
  for (long i = (long)blockIdx.x * blockDim.x + threadIdx.x; i < n4; i += stride) {
    float4 v = ((const float4*)src)[i];
    u16x4 o;
    o[0] = f2h(v.x); o[1] = f2h(v.y); o[2] = f2h(v.z); o[3] = f2h(v.w);
    ((u16x4*)dst)[i] = o;
  }
}

// ---------------------------------------------------------------------------
// QK^T — round 15 rebuild: BM=BN=128, 4 waves (2x2, wave 64x64 = MF4xNF4),
// BK=32 x 16 slots, LDS ring-3 x 16 KB = 48 KB -> 3 blocks/CU (12 waves/CU
// in 3 INDEPENDENT barrier groups — the round-14 qk was 1 lockstep block/CU,
// 3.4x off its floor). Slot schedule = pv_slot's proven pattern: frag reads,
// stage(s+2) [ring-3 safe], lgkmcnt(0), 16-MFMA cluster under setprio, ONE
// vmcnt(4) + ONE barrier per slot (drain s=14). Swizzle unchanged (64 B
// rows, chunk ^= (row>>1)&3, 2-way = free). Epilogue: L2-allocating score
// stores + fused partial row-stats over this block's 128 cols ->
// rowpart[bz][J0>>7][row] (8 J-blocks now).
// ---------------------------------------------------------------------------
__global__ __launch_bounds__(256, 3) void qk_pipe(
    const u16* __restrict__ A, u16* __restrict__ Cout,
    float2* __restrict__ rowpart, float scale) {
  extern __shared__ __align__(16) char smem[];   // 3 * 16384
  const int tid  = threadIdx.x;
  const int lane = tid & 63;
  const int w    = tid >> 6;
  const int wm   = w >> 1;        // 0..1
  const int wn   = w & 1;         // 0..1
  const int lr   = lane & 15;
  const int hi   = lane >> 4;

  const int L = blockIdx.x + (blockIdx.y << 3) + (blockIdx.z << 6);
  int bz, r;
  xcd_map<64>(L, bz, r);
  const int I0 = (r >> 3) * 128;
  const int J0 = (r & 7) * 128;
  const u16* Ab = A + (long)bz * (S_ * D_);

  // stage slot s: A-panel 8 KB (buf offset 0) + B-panel 8 KB (offset 8192)
  auto stage = [&](int s) {
    if (s >= 16) return;
    char* dst = smem + (s % 3) * 16384;
    const int k0 = s * 32;
    #pragma unroll
    for (int i = 0; i < 2; ++i) {
      int cid = i * 256 + tid;            // 0..511
      int row = cid >> 2;
      int c   = (cid & 3) ^ ((row >> 1) & 3);
      gld_lds16(Ab + (size_t)(I0 + row) * D_ + k0 + c * 8, dst + cid * 16);
    }
    #pragma unroll
    for (int i = 0; i < 2; ++i) {
      int cid = i * 256 + tid;
      int row = cid >> 2;
      int c   = (cid & 3) ^ ((row >> 1) & 3);
      gld_lds16(Ab + (size_t)(J0 + row) * D_ + k0 + c * 8, dst + 8192 + cid * 16);
    }
  };

  f32x4 acc[4][4] = {};

  stage(0); stage(1);
  asm volatile("s_waitcnt vmcnt(4)" ::: "memory");   // slot 0 landed
  __builtin_amdgcn_s_barrier();

  for (int s = 0; s < 16; ++s) {
    const char* sl = smem + (s % 3) * 16384;
    f16x8 af[4], bf[4];
    #pragma unroll
    for (int m = 0; m < 4; ++m) {
      int row = wm * 64 + m * 16 + lr;
      int cp  = hi ^ ((row >> 1) & 3);
      af[m] = *(const f16x8*)(sl + row * 64 + cp * 16);
    }
    #pragma unroll
    for (int n = 0; n < 4; ++n) {
      int row = wn * 64 + n * 16 + lr;
      int cp  = hi ^ ((row >> 1) & 3);
      bf[n] = *(const f16x8*)(sl + 8192 + row * 64 + cp * 16);
    }
    stage(s + 2);                         // ring-3: (s+2)%3 != s%3, (s+1)%3
    asm volatile("s_waitcnt lgkmcnt(0)" ::: "memory");
    __builtin_amdgcn_sched_barrier(0);
    __builtin_amdgcn_s_setprio(1);
    #pragma unroll
    for (int m = 0; m < 4; ++m)
      #pragma unroll
      for (int n = 0; n < 4; ++n)
        acc[m][n] = __builtin_amdgcn_mfma_f32_16x16x32_f16(af[m], bf[n], acc[m][n], 0, 0, 0);
    __builtin_amdgcn_s_setprio(0);
    if (s <= 13)      asm volatile("s_waitcnt vmcnt(4)" ::: "memory");
    else if (s == 14) asm volatile("s_waitcnt vmcnt(0)" ::: "memory");
    __builtin_amdgcn_s_barrier();
  }

  // ---- epilogue: score stores + fused partial row-stats (128 cols) ----
  __syncthreads();                       // ring reads done; smem reusable
  float2* part = (float2*)smem;          // [128][2]
  const float l2e = 1.4426950408889634f;
  u16* Cb = Cout + (long)bz * S_ * S_;
  const int row0 = I0 + wm * 64;
  const int col0 = J0 + wn * 64;
  #pragma unroll
  for (int m = 0; m < 4; ++m) {
    #pragma unroll
    for (int i = 0; i < 4; ++i) {
      int rl = wm * 64 + m * 16 + (hi << 2) + i;    // row within tile
      int rr = I0 + rl;
      float v[4];
      #pragma unroll
      for (int n = 0; n < 4; ++n) v[n] = acc[m][n][i] * scale;
      float mx = fmaxf(fmaxf(v[0], v[1]), fmaxf(v[2], v[3]));
      #pragma unroll
      for (int off = 1; off <= 8; off <<= 1)
        mx = fmaxf(mx, __shfl_xor(mx, off));        // reduce over 16-lane lr
      float sum = 0.f;
      #pragma unroll
      for (int n = 0; n < 4; ++n) sum += exp2f((v[n] - mx) * l2e);
      #pragma unroll
      for (int off = 1; off <= 8; off <<= 1)
        sum += __shfl_xor(sum, off);
      #pragma unroll
      for (int n = 0; n < 4; ++n)
        Cb[(size_t)rr * S_ + col0 + n * 16 + lr] = f2h(v[n]);
      if (lr == 0) part[rl * 2 + wn] = make_float2(mx, sum);
    }
  }
  __syncthreads();
  if (tid < 128) {
    float2 a = part[tid * 2], b = part[tid * 2 + 1];
    float m = fmaxf(a.x, b.x);
    float l = a.y * exp2f((a.x - m) * l2e) + b.y * exp2f((b.x - m) * l2e);
    rowpart[((long)bz * 8 + (J0 >> 7)) * S_ + I0 + tid] = make_float2(m, l);
  }
  (void)row0;
}

// ---------------------------------------------------------------------------
// pv_slot. [frozen = round 14 except mergeStat: 8 rowpart partials now]
// ---------------------------------------------------------------------------
__global__ __launch_bounds__(256, 2) void pv_slot(
    const u16* __restrict__ scores, const u16* __restrict__ VWT,
    const float2* __restrict__ rowpart,
    float* __restrict__ out, const float* __restrict__ bias) {
  extern __shared__ __align__(16) char smem[];   // A 3*8K @0, B 3*16K @24K
  const int tid  = threadIdx.x;
  const int lane = tid & 63;
  const int w    = tid >> 6;
  const int wm   = w >> 1;        // 0..1
  const int wn   = w & 1;         // 0..1
  const int lr   = lane & 15;
  const int hi   = lane >> 4;

  const int L = blockIdx.x + (blockIdx.y << 1) + (blockIdx.z << 6);
  int bz, rblk;
  xcd_map<64>(L, bz, rblk);
  const int yt = rblk >> 1;
  const int J0 = (rblk & 1) * 128;

  float* ob = out + (long)bz * MAXS_ * P_;
  if (yt >= 16) {                  // zero rows [yt*64,+64) x cols [J0,+128)
    #pragma unroll 2
    for (int i = tid; i < 64 * 32; i += 256) {
      int rr = i >> 5;
      int c4 = i & 31;
      *((float4*)(ob + (size_t)(yt * 64 + rr) * P_ + J0) + c4) =
          make_float4(0.f, 0.f, 0.f, 0.f);
    }
    return;
  }

  const int q0 = yt * 64;
  const u16* sA = scores + ((long)bz * S_ + q0) * S_;
  const u16* Vb = VWT + (long)bz * P_ * S_ + (size_t)J0 * S_;
  const float l2e = 1.4426950408889634f;

  const int ar0 = tid >> 3;
  const int ar1 = 32 + (tid >> 3);
  const int ac  = tid & 7;
  const int c0  = ac ^ (ar0 & 7);
  const int c1  = ac ^ (ar1 & 7);

  // merge the 8 per-col-tile partials for each staged row
  const float2* rp = rowpart + (long)bz * 8 * S_;
  auto mergeStat = [&](int row, float& nml, float& il) {
    float2 p[8];
    float m = -3.4e38f;
    #pragma unroll
    for (int jx = 0; jx < 8; ++jx) {
      p[jx] = rp[jx * S_ + row];
      m = fmaxf(m, p[jx].x);
    }
    float l = 0.f;
    #pragma unroll
    for (int jx = 0; jx < 8; ++jx)
      l += p[jx].y * exp2f((p[jx].x - m) * l2e);
    nml = -m * l2e;
    il  = 1.f / l;
  };
  float nml0, il0, nml1, il1;
  mergeStat(q0 + ar0, nml0, il0);
  mergeStat(q0 + ar1, nml1, il1);

  auto loadA = [&](int s, u16x8 (&r)[2]) {
    r[0] = *(const u16x8*)(sA + (size_t)ar0 * S_ + s * 64 + c0 * 8);
    r[1] = *(const u16x8*)(sA + (size_t)ar1 * S_ + s * 64 + c1 * 8);
  };
  auto writeA = [&](int buf, u16x8 (&r)[2]) {
    char* dA = smem + buf * 8192;
    u16x8 p0, p1;
    #pragma unroll
    for (int j = 0; j < 8; ++j) {
      p0[j] = f2h(exp2f(fmaf(h2f(r[0][j]), l2e, nml0)) * il0);
      p1[j] = f2h(exp2f(fmaf(h2f(r[1][j]), l2e, nml1)) * il1);
    }
    *(u16x8*)(dA + (size_t)tid * 16)         = p0;
    *(u16x8*)(dA + (size_t)(256 + tid) * 16) = p1;
  };
  auto stageB = [&](int s, int buf) {
    char* dB = smem + 24576 + buf * 16384;
    #pragma unroll
    for (int i = 0; i < 4; ++i) {
      int cid = i * 256 + tid;
      int row = cid >> 3;
      int c   = (cid & 7) ^ (row & 7);
      gld_lds16(Vb + (size_t)row * S_ + s * 64 + c * 8, dB + cid * 16);
    }
  };

  f32x4 acc[2][4] = {};
  u16x8 rA[2][2];

  loadA(0, rA[0]);
  __builtin_amdgcn_sched_barrier(0);
  stageB(0, 0);
  __builtin_amdgcn_sched_barrier(0);
  loadA(1, rA[1]);
  __builtin_amdgcn_sched_barrier(0);
  stageB(1, 1);
  __builtin_amdgcn_sched_barrier(0);
  asm volatile("s_waitcnt vmcnt(6)" ::: "memory");
  writeA(0, rA[0]);
  asm volatile("s_waitcnt lgkmcnt(0)" ::: "memory");
  __builtin_amdgcn_s_barrier();

  #pragma unroll
  for (int s = 0; s < 16; ++s) {
    const int bufR = s % 3;
    const char* aB = smem + bufR * 8192;
    const char* bB = smem + 24576 + bufR * 16384;

    f16x8 af[2][2], bf[2][4];
    #pragma unroll
    for (int kk = 0; kk < 2; ++kk) {
      #pragma unroll
      for (int m = 0; m < 2; ++m) {
        int row = wm * 32 + m * 16 + lr;
        int cp  = (kk * 4 + hi) ^ (row & 7);
        af[kk][m] = *(const f16x8*)(aB + row * 128 + cp * 16);
      }
      #pragma unroll
      for (int n = 0; n < 4; ++n) {
        int row = wn * 64 + n * 16 + lr;
        int cp  = (kk * 4 + hi) ^ (row & 7);
        bf[kk][n] = *(const f16x8*)(bB + row * 128 + cp * 16);
      }
    }

    if (s + 2 < 16) {
      loadA(s + 2, rA[s & 1]);
      __builtin_amdgcn_sched_barrier(0);
      stageB(s + 2, (s + 2) % 3);
      __builtin_amdgcn_sched_barrier(0);
    }

    __builtin_amdgcn_s_setprio(1);
    #pragma unroll
    for (int kk = 0; kk < 2; ++kk)
      #pragma unroll
      for (int m = 0; m < 2; ++m)
        #pragma unroll
        for (int n = 0; n < 4; ++n)
          acc[m][n] = __builtin_amdgcn_mfma_f32_16x16x32_f16(
              af[kk][m], bf[kk][n], acc[m][n], 0, 0, 0);
    __builtin_amdgcn_s_setprio(0);

    if (s < 15) {
      if (s <= 13) asm volatile("s_waitcnt vmcnt(6)" ::: "memory");
      else         asm volatile("s_waitcnt vmcnt(0)" ::: "memory");
      writeA((s + 1) % 3, rA[(s + 1) & 1]);
      asm volatile("s_waitcnt lgkmcnt(0)" ::: "memory");
      __builtin_amdgcn_s_barrier();
    }
  }

  float bv[4];
  #pragma unroll
  for (int n = 0; n < 4; ++n) bv[n] = bias[J0 + wn * 64 + n * 16 + lr];
  #pragma unroll
  for (int m = 0; m < 2; ++m) {
    #pragma unroll
    for (int i = 0; i < 4; ++i) {
      int rr = q0 + wm * 32 + m * 16 + (hi << 2) + i;
      #pragma unroll
      for (int n = 0; n < 4; ++n)
        ob[(size_t)rr * P_ + J0 + wn * 64 + n * 16 + lr] = acc[m][n][i] + bv[n];
    }
  }
}

// ---------------------------------------------------------------------------
// VW GEMM. [frozen, incl. round-11 swizzled decode]
// ---------------------------------------------------------------------------
template<int KK, int BM, int BN, int NW, int WNS, int BPB>
__global__ __launch_bounds__(NW * 64, 2) void gemm_nt_small(
    const u16* __restrict__ A, const u16* __restrict__ Bm,
    u16* __restrict__ C, long sAb, long sBb, long sCb, int LDC) {
  constexpr int T   = NW * 64;
  constexpr int WMS = NW / WNS;
  constexpr int MF  = BM / (WMS * 16);
  constexpr int NF  = BN / (WNS * 16);
  constexpr int LA  = BM * 8 / T;
  constexpr int LB  = BN * 8 / T;
  constexpr int SZ  = (BM + BN) * 128;
  constexpr int NT  = KK / 64;

  extern __shared__ __align__(16) char smem[];
  const int tid  = threadIdx.x;
  const int lane = tid & 63;
  const int w    = tid >> 6;
  const int wm   = w / WNS;
  const int wn   = w % WNS;
  const int lr   = lane & 15;
  const int hi   = lane >> 4;

  const int L = blockIdx.x + gridDim.x * (blockIdx.y + gridDim.y * blockIdx.z);
  int bz, r;
  xcd_map<BPB>(L, bz, r);
  const int I0 = (r / gridDim.x) * BM;
  const int J0 = (r % gridDim.x) * BN;
  const u16* Ab = A  + (long)bz * sAb;
  const u16* Bb = Bm + (long)bz * sBb;

  auto stage = [&](int buf, int k0) {
    char* sA = smem + buf * SZ;
    char* sB = sA + BM * 128;
    #pragma unroll
    for (int i = 0; i < LA; ++i) {
      int cid = i * T + tid;
      int row = cid >> 3;
      int c   = (cid & 7) ^ (row & 7);
      gld_lds16(Ab + (size_t)(I0 + row) * KK + k0 + c * 8, sA + cid * 16);
    }
    #pragma unroll
    for (int i = 0; i < LB; ++i) {
      int cid = i * T + tid;
      int row = cid >> 3;
      int c   = (cid & 7) ^ (row & 7);
      gld_lds16(Bb + (size_t)(J0 + row) * KK + k0 + c * 8, sB + cid * 16);
    }
  };

  f32x4 acc[MF][NF] = {};
  stage(0, 0);
  for (int t = 0; t < NT; ++t) {
    const char* lA = smem + (t & 1) * SZ;
    const char* lB = lA + BM * 128;
    if (t + 1 < NT) {
      stage((t + 1) & 1, (t + 1) * 64);
      asm volatile("s_waitcnt vmcnt(%0)" :: "i"(LA + LB) : "memory");
    } else {
      asm volatile("s_waitcnt vmcnt(0)" ::: "memory");
    }
    __builtin_amdgcn_s_barrier();
    __builtin_amdgcn_sched_barrier(0);
    #pragma unroll
    for (int kk = 0; kk < 2; ++kk) {
      f16x8 af[MF], bfv[NF];
      #pragma unroll
      for (int m = 0; m < MF; ++m) {
        int row = wm * (MF * 16) + m * 16 + lr;
        int cp  = (kk * 4 + hi) ^ (row & 7);
        af[m] = *(const f16x8*)(lA + ((row * 8 + cp) << 4));
      }
      #pragma unroll
      for (int n = 0; n < NF; ++n) {
        int row = wn * (NF * 16) + n * 16 + lr;
        int cp  = (kk * 4 + hi) ^ (row & 7);
        bfv[n] = *(const f16x8*)(lB + ((row * 8 + cp) << 4));
      }
      __builtin_amdgcn_s_setprio(1);
      #pragma unroll
      for (int m = 0; m < MF; ++m)
        #pragma unroll
        for (int n = 0; n < NF; ++n)
          acc[m][n] = __builtin_amdgcn_mfma_f32_16x16x32_f16(af[m], bfv[n], acc[m][n], 0, 0, 0);
      __builtin_amdgcn_s_setprio(0);
    }
    __builtin_amdgcn_sched_barrier(0);
    __builtin_amdgcn_s_barrier();
  }

  const int row0 = I0 + wm * (MF * 16);
  const int col0 = J0 + wn * (NF * 16);
  #pragma unroll
  for (int m = 0; m < MF; ++m)
    #pragma unroll
    for (int i = 0; i < 4; ++i) {
      int rr = row0 + m * 16 + (hi << 2) + i;
      #pragma unroll
      for (int n = 0; n < NF; ++n)
        C[(long)bz * sCb + (size_t)rr * LDC + col0 + n * 16 + lr] = f2h(acc[m][n][i]);
    }
}

// ---------------------------------------------------------------------------
extern "C" void kernel_launch(void* const* d_in, const int* in_sizes, int n_in,
                              void* d_out, int out_size, void* d_ws, size_t ws_size,
                              hipStream_t stream) {
  const float* data = (const float*)d_in[0];   // [16][1024][512]
  const float* W    = (const float*)d_in[1];   // [256][512]
  const float* bias = (const float*)d_in[2];   // [256]
  float* out = (float*)d_out;                  // [16][2048][256]
  char*  ws  = (char*)d_ws;

  const size_t MB = 1024 * 1024;
  u16*    dataH   = (u16*)(ws);                // 16 MB  [B][S][D] f16
  u16*    Wh      = (u16*)(ws + 16 * MB);      // 256 KB [P][D] f16
  u16*    scoresH = (u16*)(ws + 17 * MB);      // 32 MB  [B][S][S] f16
  u16*    VWT     = (u16*)(ws + 49 * MB);      // 8 MB   [B][P][S] f16
  float2* rowpart = (float2*)(ws + 57 * MB);   // 1 MB   [B][8][S] (m, l)

  const float scale = 0.04419417382415922f;    // 1/sqrt(512)

  constexpr int SMEM_QK = 3 * 16384;             // 48 KB
  constexpr int SMEM_PV = 3 * 8192 + 3 * 16384;  // 72 KB
  constexpr int SMEM_VW = 2 * (64 + 128) * 128;  // 48 KB

  (void)hipFuncSetAttribute((const void*)&qk_pipe,
                      hipFuncAttributeMaxDynamicSharedMemorySize, SMEM_QK);
  (void)hipFuncSetAttribute((const void*)&pv_slot,
                      hipFuncAttributeMaxDynamicSharedMemorySize, SMEM_PV);
  (void)hipFuncSetAttribute((const void*)&gemm_nt_small<512, 64, 128, 4, 2, 32>,
                      hipFuncAttributeMaxDynamicSharedMemorySize, SMEM_VW);

  convert_f16_kernel<<<2048, 256, 0, stream>>>(data, dataH, (long)B_ * S_ * D_ / 4);
  convert_f16_kernel<<<64, 256, 0, stream>>>(W, Wh, (long)P_ * D_ / 4);

  // VWT[b] = Wh (256x512) @ dataH[b]^T -> [256][1024] f16
  gemm_nt_small<512, 64, 128, 4, 2, 32><<<dim3(8, 4, 16), 256, SMEM_VW, stream>>>(
      Wh, dataH, VWT, 0L, (long)S_ * D_, (long)P_ * S_, S_);

  // scoresH + rowpart = scale * dataH[b] @ dataH[b]^T (128^2 tiles, 3/CU)
  qk_pipe<<<dim3(8, 8, 16), 256, SMEM_QK, stream>>>(
      dataH, scoresH, rowpart, scale);

  // out[b][:S] = softmax(scoresH[b]) @ VWT[b]^T + bias; tail rows zeroed
  pv_slot<<<dim3(2, 32, 16), 256, SMEM_PV, stream>>>(
      scoresH, VWT, rowpart, out, bias);
}

// Round 16
// 78.247 us; speedup vs baseline: 1.0277x; 1.0277x over previous
//
#include <hip/hip_runtime.h>
#include <cstdint>
#include <cstddef>

// Problem constants
#define B_    16
#define S_    1024
#define D_    512
#define P_    256
#define MAXS_ 2048

typedef unsigned short u16;
typedef unsigned int   u32;
typedef _Float16 f16;
typedef _Float16 f16x8 __attribute__((ext_vector_type(8)));
typedef float  f32x4  __attribute__((ext_vector_type(4)));
typedef unsigned short u16x4 __attribute__((ext_vector_type(4)));
typedef unsigned short u16x8 __attribute__((ext_vector_type(8)));

__device__ __forceinline__ void gld_lds16(const void* g, void* l) {
  __builtin_amdgcn_global_load_lds(
      (const __attribute__((address_space(1))) u32*)g,
      (__attribute__((address_space(3))) u32*)l, 16, 0, 0);
}

__device__ __forceinline__ u16 f2h(float f) {
  return __builtin_bit_cast(u16, (f16)f);
}
__device__ __forceinline__ float h2f(u16 h) {
  return (float)__builtin_bit_cast(f16, h);
}

// Batch-affinity XCD swizzle (round 11, kept): XCD t owns batches 2t, 2t+1.
template<int BPB>
__device__ __forceinline__ void xcd_map(int L, int& bz, int& r) {
  const int t = L & 7;
  const int j = L >> 3;
  bz = (t << 1) | (j / BPB);
  r  = j % BPB;
}

// ---------------------------------------------------------------------------
// f32 -> f16 convert (data, W)  [frozen]
// ---------------------------------------------------------------------------
__global__ void convert_f16_kernel(const float* __restrict__ src, u16* __restrict__ dst, long n4) {
  long stride = (long)gridDim.x * blockDim.x;
  for (long i = (long)blockIdx.x * blockDim.x + threadIdx.x; i < n4; i += stride) {
    float4 v = ((const float4*)src)[i];
    u16x4 o;
    o[0] = f2h(v.x); o[1] = f2h(v.y); o[2] = f2h(v.z); o[3] = f2h(v.w);
    ((u16x4*)dst)[i] = o;
  }
}

// ---------------------------------------------------------------------------
// QK^T — round-14 256^2 body; round-16 CHANGE: removed the forced
// lgkmcnt(0)+sched_barrier(0) drain before the MFMA cluster (was
// re-creating m141's order-pinning pathology). Compiler now emits counted
// lgkmcnt between ds_read and MFMA — frag reads overlap MFMA issue. Slot
// boundary keeps {vmcnt(counted, "memory" clobber pins memory ops) ->
// s_barrier -> sched_barrier} so next-slot reads can't hoist. Ring-4 /
// vmcnt ladder unchanged. Epilogue frozen (L2-allocating score stores +
// fused partial row-stats, rowpart[B][4][S]).
// ---------------------------------------------------------------------------
__global__ __launch_bounds__(512, 2) void qk_pipe(
    const u16* __restrict__ A, u16* __restrict__ Cout,
    float2* __restrict__ rowpart, float scale) {
  extern __shared__ __align__(16) char smem[];   // 4 * 32768
  const int tid  = threadIdx.x;
  const int lane = tid & 63;
  const int w    = tid >> 6;
  const int wm   = w >> 2;        // 0..1
  const int wn   = w & 3;         // 0..3
  const int lr   = lane & 15;
  const int hi   = lane >> 4;

  const int L = blockIdx.x + (blockIdx.y << 2) + (blockIdx.z << 4);
  int bz, r;
  xcd_map<16>(L, bz, r);
  const int I0 = (r >> 2) * 256;
  const int J0 = (r & 3) * 256;
  const u16* Ab = A + (long)bz * (S_ * D_);

  auto stageP = [&](int s, int part) {
    if (s >= 16) return;
    char* dst = smem + (s & 3) * 32768 + part * 16384;
    const int base = part ? J0 : I0;
    const int k0 = s * 32;
    #pragma unroll
    for (int i = 0; i < 2; ++i) {
      int cid   = i * 512 + tid;
      int inner = cid >> 2;
      int c     = (cid & 3) ^ ((inner >> 1) & 3);
      gld_lds16(Ab + (size_t)(base + inner) * D_ + k0 + c * 8, dst + cid * 16);
    }
  };

  f32x4 acc[8][4] = {};

  stageP(0, 0); stageP(0, 1);
  stageP(1, 0); stageP(1, 1);
  stageP(2, 0); stageP(2, 1);
  asm volatile("s_waitcnt vmcnt(8)" ::: "memory");   // slot 0 landed
  __builtin_amdgcn_s_barrier();
  __builtin_amdgcn_sched_barrier(0);

  for (int s = 0; s < 16; ++s) {
    const char* sl = smem + (s & 3) * 32768;
    f16x8 af0[4], af1[4], bf[4];
    #pragma unroll
    for (int mq = 0; mq < 4; ++mq) {
      int row = wm * 128 + mq * 16 + lr;
      int cp  = hi ^ ((row >> 1) & 3);
      af0[mq] = *(const f16x8*)(sl + row * 64 + cp * 16);
    }
    #pragma unroll
    for (int mq = 0; mq < 4; ++mq) {
      int row = wm * 128 + 64 + mq * 16 + lr;
      int cp  = hi ^ ((row >> 1) & 3);
      af1[mq] = *(const f16x8*)(sl + row * 64 + cp * 16);
    }
    #pragma unroll
    for (int n = 0; n < 4; ++n) {
      int row = wn * 64 + n * 16 + lr;
      int cp  = hi ^ ((row >> 1) & 3);
      bf[n] = *(const f16x8*)(sl + 16384 + row * 64 + cp * 16);
    }
    stageP(s + 3, 0);
    stageP(s + 3, 1);
    // NO lgkmcnt(0)/sched_barrier here: compiler emits counted lgkmcnt so
    // MFMA issue overlaps the tail of the frag reads (the m97 pattern).
    __builtin_amdgcn_s_setprio(1);
    #pragma unroll
    for (int mq = 0; mq < 4; ++mq)
      #pragma unroll
      for (int n = 0; n < 4; ++n)
        acc[mq][n] = __builtin_amdgcn_mfma_f32_16x16x32_f16(af0[mq], bf[n], acc[mq][n], 0, 0, 0);
    #pragma unroll
    for (int mq = 0; mq < 4; ++mq)
      #pragma unroll
      for (int n = 0; n < 4; ++n)
        acc[4 + mq][n] = __builtin_amdgcn_mfma_f32_16x16x32_f16(af1[mq], bf[n], acc[4 + mq][n], 0, 0, 0);
    __builtin_amdgcn_s_setprio(0);
    if (s <= 12)      asm volatile("s_waitcnt vmcnt(8)" ::: "memory");
    else if (s == 13) asm volatile("s_waitcnt vmcnt(4)" ::: "memory");
    else if (s == 14) asm volatile("s_waitcnt vmcnt(0)" ::: "memory");
    __builtin_amdgcn_s_barrier();
    __builtin_amdgcn_sched_barrier(0);
  }

  // ---- epilogue: L2-allocating score stores + fused partial row-stats ----
  __syncthreads();                       // ring reads done; smem reusable
  float2* part = (float2*)smem;          // [256][4]
  const float l2e = 1.4426950408889634f;
  u16* Cb = Cout + (long)bz * S_ * S_;
  const int row0 = I0 + wm * 128;
  const int col0 = J0 + wn * 64;
  #pragma unroll
  for (int m = 0; m < 8; ++m) {
    #pragma unroll
    for (int i = 0; i < 4; ++i) {
      int rr = row0 + m * 16 + (hi << 2) + i;
      float v[4];
      #pragma unroll
      for (int n = 0; n < 4; ++n) v[n] = acc[m][n][i] * scale;
      float mx = fmaxf(fmaxf(v[0], v[1]), fmaxf(v[2], v[3]));
      #pragma unroll
      for (int off = 1; off <= 8; off <<= 1)
        mx = fmaxf(mx, __shfl_xor(mx, off));       // reduce over lr group
      float sum = 0.f;
      #pragma unroll
      for (int n = 0; n < 4; ++n) sum += exp2f((v[n] - mx) * l2e);
      #pragma unroll
      for (int off = 1; off <= 8; off <<= 1)
        sum += __shfl_xor(sum, off);
      #pragma unroll
      for (int n = 0; n < 4; ++n)
        Cb[(size_t)rr * S_ + col0 + n * 16 + lr] = f2h(v[n]);
      if (lr == 0)
        part[(wm * 128 + m * 16 + (hi << 2) + i) * 4 + wn] = make_float2(mx, sum);
    }
  }
  __syncthreads();
  if (tid < 256) {
    float2 a = part[tid * 4],     b = part[tid * 4 + 1];
    float2 c = part[tid * 4 + 2], d = part[tid * 4 + 3];
    float m = fmaxf(fmaxf(a.x, b.x), fmaxf(c.x, d.x));
    float l = a.y * exp2f((a.x - m) * l2e) + b.y * exp2f((b.x - m) * l2e)
            + c.y * exp2f((c.x - m) * l2e) + d.y * exp2f((d.x - m) * l2e);
    rowpart[((long)bz * 4 + (J0 >> 8)) * S_ + I0 + tid] = make_float2(m, l);
  }
}

// ---------------------------------------------------------------------------
// pv_slot — round-14 body; round-16 CHANGE: (a) removed forced lgkmcnt(0)+
// sched_barrier before MFMA; (b) moved {vmcnt(6), writeA(s+1)} BEFORE the
// MFMA cluster so the 32-exp2 VALU chain and ds_writes co-issue with MFMA
// (separate pipes, m114) instead of sitting serially in the slot tail.
// lgkmcnt(0) before the barrier retained (ds_write completion). Ring-3 /
// vmcnt ladder unchanged.
// ---------------------------------------------------------------------------
__global__ __launch_bounds__(256, 2) void pv_slot(
    const u16* __restrict__ scores, const u16* __restrict__ VWT,
    const float2* __restrict__ rowpart,
    float* __restrict__ out, const float* __restrict__ bias) {
  extern __shared__ __align__(16) char smem[];   // A 3*8K @0, B 3*16K @24K
  const int tid  = threadIdx.x;
  const int lane = tid & 63;
  const int w    = tid >> 6;
  const int wm   = w >> 1;        // 0..1
  const int wn   = w & 1;         // 0..1
  const int lr   = lane & 15;
  const int hi   = lane >> 4;

  const int L = blockIdx.x + (blockIdx.y << 1) + (blockIdx.z << 6);
  int bz, rblk;
  xcd_map<64>(L, bz, rblk);
  const int yt = rblk >> 1;
  const int J0 = (rblk & 1) * 128;

  float* ob = out + (long)bz * MAXS_ * P_;
  if (yt >= 16) {                  // zero rows [yt*64,+64) x cols [J0,+128)
    #pragma unroll 2
    for (int i = tid; i < 64 * 32; i += 256) {
      int rr = i >> 5;
      int c4 = i & 31;
      *((float4*)(ob + (size_t)(yt * 64 + rr) * P_ + J0) + c4) =
          make_float4(0.f, 0.f, 0.f, 0.f);
    }
    return;
  }

  const int q0 = yt * 64;
  const u16* sA = scores + ((long)bz * S_ + q0) * S_;
  const u16* Vb = VWT + (long)bz * P_ * S_ + (size_t)J0 * S_;
  const float l2e = 1.4426950408889634f;

  const int ar0 = tid >> 3;
  const int ar1 = 32 + (tid >> 3);
  const int ac  = tid & 7;
  const int c0  = ac ^ (ar0 & 7);
  const int c1  = ac ^ (ar1 & 7);

  // merge the 4 per-col-tile partials for each staged row
  const float2* rp = rowpart + (long)bz * 4 * S_;
  auto mergeStat = [&](int row, float& nml, float& il) {
    float2 a = rp[row],          b = rp[S_ + row];
    float2 c = rp[2 * S_ + row], d = rp[3 * S_ + row];
    float m = fmaxf(fmaxf(a.x, b.x), fmaxf(c.x, d.x));
    float l = a.y * exp2f((a.x - m) * l2e) + b.y * exp2f((b.x - m) * l2e)
            + c.y * exp2f((c.x - m) * l2e) + d.y * exp2f((d.x - m) * l2e);
    nml = -m * l2e;
    il  = 1.f / l;
  };
  float nml0, il0, nml1, il1;
  mergeStat(q0 + ar0, nml0, il0);
  mergeStat(q0 + ar1, nml1, il1);

  auto loadA = [&](int s, u16x8 (&r)[2]) {
    r[0] = *(const u16x8*)(sA + (size_t)ar0 * S_ + s * 64 + c0 * 8);
    r[1] = *(const u16x8*)(sA + (size_t)ar1 * S_ + s * 64 + c1 * 8);
  };
  auto writeA = [&](int buf, u16x8 (&r)[2]) {
    char* dA = smem + buf * 8192;
    u16x8 p0, p1;
    #pragma unroll
    for (int j = 0; j < 8; ++j) {
      p0[j] = f2h(exp2f(fmaf(h2f(r[0][j]), l2e, nml0)) * il0);
      p1[j] = f2h(exp2f(fmaf(h2f(r[1][j]), l2e, nml1)) * il1);
    }
    *(u16x8*)(dA + (size_t)tid * 16)         = p0;
    *(u16x8*)(dA + (size_t)(256 + tid) * 16) = p1;
  };
  auto stageB = [&](int s, int buf) {
    char* dB = smem + 24576 + buf * 16384;
    #pragma unroll
    for (int i = 0; i < 4; ++i) {
      int cid = i * 256 + tid;
      int row = cid >> 3;
      int c   = (cid & 7) ^ (row & 7);
      gld_lds16(Vb + (size_t)row * S_ + s * 64 + c * 8, dB + cid * 16);
    }
  };

  f32x4 acc[2][4] = {};
  u16x8 rA[2][2];

  // prologue: slots 0,1 in flight; slot-0 A written
  loadA(0, rA[0]);
  stageB(0, 0);
  loadA(1, rA[1]);
  stageB(1, 1);
  asm volatile("s_waitcnt vmcnt(6)" ::: "memory");   // slot-0 group landed
  writeA(0, rA[0]);
  asm volatile("s_waitcnt lgkmcnt(0)" ::: "memory");
  __builtin_amdgcn_s_barrier();
  __builtin_amdgcn_sched_barrier(0);

  #pragma unroll
  for (int s = 0; s < 16; ++s) {
    const int bufR = s % 3;
    const char* aB = smem + bufR * 8192;
    const char* bB = smem + 24576 + bufR * 16384;

    f16x8 af[2][2], bf[2][4];
    #pragma unroll
    for (int kk = 0; kk < 2; ++kk) {
      #pragma unroll
      for (int m = 0; m < 2; ++m) {
        int row = wm * 32 + m * 16 + lr;
        int cp  = (kk * 4 + hi) ^ (row & 7);
        af[kk][m] = *(const f16x8*)(aB + row * 128 + cp * 16);
      }
      #pragma unroll
      for (int n = 0; n < 4; ++n) {
        int row = wn * 64 + n * 16 + lr;
        int cp  = (kk * 4 + hi) ^ (row & 7);
        bf[kk][n] = *(const f16x8*)(bB + row * 128 + cp * 16);
      }
    }

    if (s + 2 < 16) {                  // issue slot s+2
      loadA(s + 2, rA[s & 1]);
      stageB(s + 2, (s + 2) % 3);
    }

    if (s < 15) {                      // land slot s+1, write its P tile
      if (s <= 13) asm volatile("s_waitcnt vmcnt(6)" ::: "memory");
      else         asm volatile("s_waitcnt vmcnt(0)" ::: "memory");
      writeA((s + 1) % 3, rA[(s + 1) & 1]);   // exp2 VALU co-issues w/ MFMA
    }

    __builtin_amdgcn_s_setprio(1);
    #pragma unroll
    for (int kk = 0; kk < 2; ++kk)
      #pragma unroll
      for (int m = 0; m < 2; ++m)
        #pragma unroll
        for (int n = 0; n < 4; ++n)
          acc[m][n] = __builtin_amdgcn_mfma_f32_16x16x32_f16(
              af[kk][m], bf[kk][n], acc[m][n], 0, 0, 0);
    __builtin_amdgcn_s_setprio(0);

    if (s < 15) {
      asm volatile("s_waitcnt lgkmcnt(0)" ::: "memory");   // ds_writes done
      __builtin_amdgcn_s_barrier();
      __builtin_amdgcn_sched_barrier(0);
    }
  }

  float bv[4];
  #pragma unroll
  for (int n = 0; n < 4; ++n) bv[n] = bias[J0 + wn * 64 + n * 16 + lr];
  #pragma unroll
  for (int m = 0; m < 2; ++m) {
    #pragma unroll
    for (int i = 0; i < 4; ++i) {
      int rr = q0 + wm * 32 + m * 16 + (hi << 2) + i;
      #pragma unroll
      for (int n = 0; n < 4; ++n)
        ob[(size_t)rr * P_ + J0 + wn * 64 + n * 16 + lr] = acc[m][n][i] + bv[n];
    }
  }
}

// ---------------------------------------------------------------------------
// VW GEMM. [frozen, incl. round-11 swizzled decode]
// ---------------------------------------------------------------------------
template<int KK, int BM, int BN, int NW, int WNS, int BPB>
__global__ __launch_bounds__(NW * 64, 2) void gemm_nt_small(
    const u16* __restrict__ A, const u16* __restrict__ Bm,
    u16* __restrict__ C, long sAb, long sBb, long sCb, int LDC) {
  constexpr int T   = NW * 64;
  constexpr int WMS = NW / WNS;
  constexpr int MF  = BM / (WMS * 16);
  constexpr int NF  = BN / (WNS * 16);
  constexpr int LA  = BM * 8 / T;
  constexpr int LB  = BN * 8 / T;
  constexpr int SZ  = (BM + BN) * 128;
  constexpr int NT  = KK / 64;

  extern __shared__ __align__(16) char smem[];
  const int tid  = threadIdx.x;
  const int lane = tid & 63;
  const int w    = tid >> 6;
  const int wm   = w / WNS;
  const int wn   = w % WNS;
  const int lr   = lane & 15;
  const int hi   = lane >> 4;

  const int L = blockIdx.x + gridDim.x * (blockIdx.y + gridDim.y * blockIdx.z);
  int bz, r;
  xcd_map<BPB>(L, bz, r);
  const int I0 = (r / gridDim.x) * BM;
  const int J0 = (r % gridDim.x) * BN;
  const u16* Ab = A  + (long)bz * sAb;
  const u16* Bb = Bm + (long)bz * sBb;

  auto stage = [&](int buf, int k0) {
    char* sA = smem + buf * SZ;
    char* sB = sA + BM * 128;
    #pragma unroll
    for (int i = 0; i < LA; ++i) {
      int cid = i * T + tid;
      int row = cid >> 3;
      int c   = (cid & 7) ^ (row & 7);
      gld_lds16(Ab + (size_t)(I0 + row) * KK + k0 + c * 8, sA + cid * 16);
    }
    #pragma unroll
    for (int i = 0; i < LB; ++i) {
      int cid = i * T + tid;
      int row = cid >> 3;
      int c   = (cid & 7) ^ (row & 7);
      gld_lds16(Bb + (size_t)(J0 + row) * KK + k0 + c * 8, sB + cid * 16);
    }
  };

  f32x4 acc[MF][NF] = {};
  stage(0, 0);
  for (int t = 0; t < NT; ++t) {
    const char* lA = smem + (t & 1) * SZ;
    const char* lB = lA + BM * 128;
    if (t + 1 < NT) {
      stage((t + 1) & 1, (t + 1) * 64);
      asm volatile("s_waitcnt vmcnt(%0)" :: "i"(LA + LB) : "memory");
    } else {
      asm volatile("s_waitcnt vmcnt(0)" ::: "memory");
    }
    __builtin_amdgcn_s_barrier();
    __builtin_amdgcn_sched_barrier(0);
    #pragma unroll
    for (int kk = 0; kk < 2; ++kk) {
      f16x8 af[MF], bfv[NF];
      #pragma unroll
      for (int m = 0; m < MF; ++m) {
        int row = wm * (MF * 16) + m * 16 + lr;
        int cp  = (kk * 4 + hi) ^ (row & 7);
        af[m] = *(const f16x8*)(lA + ((row * 8 + cp) << 4));
      }
      #pragma unroll
      for (int n = 0; n < NF; ++n) {
        int row = wn * (NF * 16) + n * 16 + lr;
        int cp  = (kk * 4 + hi) ^ (row & 7);
        bfv[n] = *(const f16x8*)(lB + ((row * 8 + cp) << 4));
      }
      __builtin_amdgcn_s_setprio(1);
      #pragma unroll
      for (int m = 0; m < MF; ++m)
        #pragma unroll
        for (int n = 0; n < NF; ++n)
          acc[m][n] = __builtin_amdgcn_mfma_f32_16x16x32_f16(af[m], bfv[n], acc[m][n], 0, 0, 0);
      __builtin_amdgcn_s_setprio(0);
    }
    __builtin_amdgcn_sched_barrier(0);
    __builtin_amdgcn_s_barrier();
  }

  const int row0 = I0 + wm * (MF * 16);
  const int col0 = J0 + wn * (NF * 16);
  #pragma unroll
  for (int m = 0; m < MF; ++m)
    #pragma unroll
    for (int i = 0; i < 4; ++i) {
      int rr = row0 + m * 16 + (hi << 2) + i;
      #pragma unroll
      for (int n = 0; n < NF; ++n)
        C[(long)bz * sCb + (size_t)rr * LDC + col0 + n * 16 + lr] = f2h(acc[m][n][i]);
    }
}

// ---------------------------------------------------------------------------
extern "C" void kernel_launch(void* const* d_in, const int* in_sizes, int n_in,
                              void* d_out, int out_size, void* d_ws, size_t ws_size,
                              hipStream_t stream) {
  const float* data = (const float*)d_in[0];   // [16][1024][512]
  const float* W    = (const float*)d_in[1];   // [256][512]
  const float* bias = (const float*)d_in[2];   // [256]
  float* out = (float*)d_out;                  // [16][2048][256]
  char*  ws  = (char*)d_ws;

  const size_t MB = 1024 * 1024;
  u16*    dataH   = (u16*)(ws);                // 16 MB  [B][S][D] f16
  u16*    Wh      = (u16*)(ws + 16 * MB);      // 256 KB [P][D] f16
  u16*    scoresH = (u16*)(ws + 17 * MB);      // 32 MB  [B][S][S] f16
  u16*    VWT     = (u16*)(ws + 49 * MB);      // 8 MB   [B][P][S] f16
  float2* rowpart = (float2*)(ws + 57 * MB);   // 512 KB [B][4][S] (m, l)

  const float scale = 0.04419417382415922f;    // 1/sqrt(512)

  constexpr int SMEM_QK = 4 * 32768;             // 128 KB
  constexpr int SMEM_PV = 3 * 8192 + 3 * 16384;  // 72 KB
  constexpr int SMEM_VW = 2 * (64 + 128) * 128;  // 48 KB

  (void)hipFuncSetAttribute((const void*)&qk_pipe,
                      hipFuncAttributeMaxDynamicSharedMemorySize, SMEM_QK);
  (void)hipFuncSetAttribute((const void*)&pv_slot,
                      hipFuncAttributeMaxDynamicSharedMemorySize, SMEM_PV);
  (void)hipFuncSetAttribute((const void*)&gemm_nt_small<512, 64, 128, 4, 2, 32>,
                      hipFuncAttributeMaxDynamicSharedMemorySize, SMEM_VW);

  convert_f16_kernel<<<2048, 256, 0, stream>>>(data, dataH, (long)B_ * S_ * D_ / 4);
  convert_f16_kernel<<<64, 256, 0, stream>>>(W, Wh, (long)P_ * D_ / 4);

  // VWT[b] = Wh (256x512) @ dataH[b]^T -> [256][1024] f16
  gemm_nt_small<512, 64, 128, 4, 2, 32><<<dim3(8, 4, 16), 256, SMEM_VW, stream>>>(
      Wh, dataH, VWT, 0L, (long)S_ * D_, (long)P_ * S_, S_);

  // scoresH + rowpart = scale * dataH[b] @ dataH[b]^T, with fused row-stats
  qk_pipe<<<dim3(4, 4, 16), 512, SMEM_QK, stream>>>(
      dataH, scoresH, rowpart, scale);

  // out[b][:S] = softmax(scoresH[b]) @ VWT[b]^T + bias; tail rows zeroed
  pv_slot<<<dim3(2, 32, 16), 256, SMEM_PV, stream>>>(
      scoresH, VWT, rowpart, out, bias);
}